// Round 10
// baseline (2194.024 us; speedup 1.0000x reference)
//
#include <hip/hip_runtime.h>

using u16 = unsigned short;
using u32 = unsigned int;

typedef _Float16 f16x2 __attribute__((ext_vector_type(2)));
typedef _Float16 f16x8 __attribute__((ext_vector_type(8)));
typedef float    f32x4 __attribute__((ext_vector_type(4)));

__device__ __forceinline__ u16 f16bits(float x) {
  union { _Float16 h; u16 u; } r; r.h = (_Float16)x; return r.u;
}
__device__ __forceinline__ float h2f(u16 v) {
  union { u16 u; _Float16 h; } r; r.u = v; return (float)r.h;
}
__device__ __forceinline__ u32 pack2(float a, float b) {
  union { f16x2 h; u32 u; } r; r.h.x = (_Float16)a; r.h.y = (_Float16)b; return r.u;
}
__device__ __forceinline__ float fdot2a(u32 a, u32 b, float c) {
  union { u32 u; f16x2 h; } ua, ub; ua.u = a; ub.u = b;
#if __has_builtin(__builtin_amdgcn_fdot2)
  return __builtin_amdgcn_fdot2(ua.h, ub.h, c, false);
#else
  return c + (float)ua.h.x * (float)ub.h.x + (float)ua.h.y * (float)ub.h.y;
#endif
}
__device__ __forceinline__ float sigmoidf_(float x) { return 1.0f / (1.0f + __expf(-x)); }
__device__ __forceinline__ float tanhf_(float x)    { return 1.0f - 2.0f / (__expf(2.0f * x) + 1.0f); }

__device__ __forceinline__ f16x8 lds16(const u16* p) {
  union { uint4 u; f16x8 h; } r; r.u = *(const uint4*)p; return r.h;
}

// ---------------- prep: build f16 weight layouts + zero state ----------------
// WxT[n][k]   : [1024][256] f16, transposed input-proj weights
// Whpp[i4][t] : [32][1024] uint4 — per-(rec-)thread gathered W_h pair groups.
//   NEW mapping (wave-owns-quarter): thread t: w=t>>6, l=t&63, grp=w>>2,
//   qw=w&3; col(cc)=grp*256+l*4+cc; i4=cc*8+pp; element e of uint4 = f16x2
//   pair kk = qw*32+pp*4+e of column col.
// h16s        : [128][128] u32 pairs of h state, zeroed
// c_s         : [128][256] f32, zeroed
__global__ void lstm_prep(const float* __restrict__ Wxi, const float* __restrict__ Wxf,
                          const float* __restrict__ Wxg, const float* __restrict__ Wxo,
                          const float* __restrict__ Whi, const float* __restrict__ Whf,
                          const float* __restrict__ Whg, const float* __restrict__ Who,
                          u16* __restrict__ WxT, u32* __restrict__ Whpp,
                          u32* __restrict__ h16s, float* __restrict__ c_s) {
  int idx = blockIdx.x * 256 + threadIdx.x;
  if (idx < 262144) {                       // WxT
    int n = idx >> 8, k = idx & 255;
    int g = n >> 8;
    const float* W = (g == 0) ? Wxi : (g == 1) ? Wxf : (g == 2) ? Wxg : Wxo;
    WxT[idx] = f16bits(W[k * 256 + (n & 255)]);
  } else if (idx < 262144 + 131072) {       // Whpp (u32-granular writes)
    int i2 = idx - 262144;
    int e = i2 & 3, tmp = i2 >> 2;
    int t = tmp & 1023, i4 = tmp >> 10;
    int cc = i4 >> 3, pp = i4 & 7;
    int w = t >> 6, l = t & 63;
    int grp = w >> 2, qw = w & 3;
    int j = grp * 256 + l * 4 + cc;         // owned column
    int kk = qw * 32 + pp * 4 + e;          // K-pair within wave's quarter
    int g = j >> 8, col = j & 255;
    const float* W = (g == 0) ? Whi : (g == 1) ? Whf : (g == 2) ? Whg : Who;
    u32 lo = f16bits(W[(2 * kk) * 256 + col]);
    u32 hi = f16bits(W[(2 * kk + 1) * 256 + col]);
    Whpp[i2] = lo | (hi << 16);
  } else if (idx < 262144 + 131072 + 16384) {
    h16s[idx - 393216] = 0u;
  } else if (idx < 262144 + 131072 + 16384 + 32768) {
    c_s[idx - 409600] = 0.0f;
  }
}

// ---------------- input-projection GEMM (R4/R5-proven permuted epilogue) -----
// Writes PERMUTED gate layout: gates[m][ (n&255)*4 + (n>>8) ] so the act phase
// loads all 4 gate pre-acts of unit u as one uint2.
__global__ __launch_bounds__(256) void proj_gemm(
    const float* __restrict__ x, const u16* __restrict__ WxT,
    u16* __restrict__ gates, const float* __restrict__ bi,
    const float* __restrict__ bf, const float* __restrict__ bg,
    const float* __restrict__ bo, int t0, int tcShift) {
  __shared__ u16 Al[128 * 72];
  __shared__ u16 Bl[128 * 72];
  const int tid = threadIdx.x;
  const int lane = tid & 63, wv = tid >> 6;
  const int wr = wv >> 1, wc = wv & 1;
  const int m0 = blockIdx.x * 128, n0 = blockIdx.y * 128;
  const int tcMask = (1 << tcShift) - 1;
  f32x4 acc[4][4] = {};
  for (int k0 = 0; k0 < 256; k0 += 64) {
#pragma unroll
    for (int p = 0; p < 8; ++p) {
      int flat = p * 256 + tid;
      int r = flat >> 4, cc = flat & 15;
      int m = m0 + r;
      int b = m >> tcShift, tc = m & tcMask;
      const float4 xv = *(const float4*)(x + (size_t)(b * 1024 + t0 + tc) * 256 + k0 + cc * 4);
      uint2 w2 = make_uint2(pack2(xv.x, xv.y), pack2(xv.z, xv.w));
      *(uint2*)&Al[r * 72 + cc * 4] = w2;
    }
#pragma unroll
    for (int p = 0; p < 8; ++p) {
      int flat = p * 256 + tid;
      int r = flat >> 4, cc = flat & 15;
      uint2 w2 = *(const uint2*)(WxT + (size_t)(n0 + r) * 256 + k0 + cc * 4);
      *(uint2*)&Bl[r * 72 + cc * 4] = w2;
    }
    __syncthreads();
#pragma unroll
    for (int kk = 0; kk < 64; kk += 32) {
      f16x8 af[4], bfr[4];
#pragma unroll
      for (int i = 0; i < 4; ++i) {
        af[i]  = lds16(&Al[(wr * 64 + i * 16 + (lane & 15)) * 72 + kk + (lane >> 4) * 8]);
        bfr[i] = lds16(&Bl[(wc * 64 + i * 16 + (lane & 15)) * 72 + kk + (lane >> 4) * 8]);
      }
#pragma unroll
      for (int mi = 0; mi < 4; ++mi)
#pragma unroll
        for (int ni = 0; ni < 4; ++ni)
          acc[mi][ni] = __builtin_amdgcn_mfma_f32_16x16x32_f16(af[mi], bfr[ni], acc[mi][ni], 0, 0, 0);
    }
    __syncthreads();
  }
#pragma unroll
  for (int ni = 0; ni < 4; ++ni) {
    int n = n0 + wc * 64 + ni * 16 + (lane & 15);
    int g = n >> 8;
    const float* bp = (g == 0) ? bi : (g == 1) ? bf : (g == 2) ? bg : bo;
    float bias = bp[n & 255];
    const int nperm = (n & 255) * 4 + g;
#pragma unroll
    for (int mi = 0; mi < 4; ++mi) {
#pragma unroll
      for (int ri = 0; ri < 4; ++ri) {
        int m = m0 + wr * 64 + mi * 16 + (lane >> 4) * 4 + ri;
        gates[(size_t)m * 1024 + nperm] = f16bits(acc[mi][ni][ri] + bias);
      }
    }
  }
}

// ---------------- persistent per-batch recurrence (SGPR-h variant) -----------
// 1024 threads, 16 waves = 4 colgroups x 4 K-quarters. Wave w: grp=w>>2,
// qw=w&3. Thread owns cols jb..jb+3 (jb=grp*256+l*4), K-pairs qw*32..+31.
// h for the wave's quarter is WAVE-UNIFORM: 1 ds_read_b128 (8 lines, broadcast)
// + 32 v_readlane -> 32 SGPRs; dots take SGPR h + AGPR/VGPR weight.
// Partial z staged to zpart[4][1024] via ONE ds_write_b128/thread; act phase
// (t<256) sums the 4 quarters, does gate math, writes h pair. 2 barriers/step.
__global__ __launch_bounds__(1024) void lstm_rec(
    const u32* __restrict__ Whpp, const u16* __restrict__ gates,
    u32* __restrict__ h16s, float* __restrict__ c_s,
    const float* __restrict__ Why, const float* __restrict__ by,
    float* __restrict__ out, int Tc, int last) {
  extern __shared__ unsigned char smem[];
  uint4* ldsW  = (uint4*)smem;                      // [8][1024] uint4 = 131072 B
  u32*   hq    = (u32*)(smem + 131072);             // [2][4*40] u32   = 1280 B
  float* zpart = (float*)(smem + 131072 + 1280);    // [4][1024] f32   = 16384 B
  const int b = blockIdx.x, t = threadIdx.x;
  const int l = t & 63, w = t >> 6;
  const int grp = w >> 2, qw = w & 3;
  const int jb = grp * 256 + l * 4;                 // first of 4 owned cols

  // gather weights: 32 coalesced uint4 loads; pp<6 -> regs, pp>=6 -> LDS
  u32 wreg[96];
  const uint4* Wp4 = (const uint4*)Whpp;
#pragma unroll
  for (int i4 = 0; i4 < 32; ++i4) {
    uint4 v = Wp4[i4 * 1024 + t];
    const int cc = i4 >> 3, pp = i4 & 7;
    if (pp < 6) {
      wreg[cc * 24 + pp * 4 + 0] = v.x;
      wreg[cc * 24 + pp * 4 + 1] = v.y;
      wreg[cc * 24 + pp * 4 + 2] = v.z;
      wreg[cc * 24 + pp * 4 + 3] = v.w;
    } else {
      ldsW[(cc * 2 + (pp - 6)) * 1024 + t] = v;
    }
  }
  if (t < 128) hq[(t >> 5) * 40 + (t & 31)] = h16s[b * 128 + t];
  float c = 0.0f;
  uint2 pre = make_uint2(0u, 0u);
  const u16* gxp = gates + (size_t)b * Tc * 1024 + t * 4;  // permuted layout
  if (t < 256) {
    c = c_s[b * 256 + t];
    pre = *(const uint2*)gxp;
  }
  int buf = 0;
  __syncthreads();

  for (int tc = 0; tc < Tc; ++tc) {
    // ---- h fetch: one b128 per wave (lane l reads 16B line l&7 of quarter)
    const uint4 hv4 = *(const uint4*)(hq + buf * 160 + qw * 40 + (l & 7) * 4);
    // ---- broadcast to SGPRs (SALU pipe)
    u32 sh[32];
#pragma unroll
    for (int i = 0; i < 8; ++i) {
      sh[4 * i + 0] = (u32)__builtin_amdgcn_readlane((int)hv4.x, i);
      sh[4 * i + 1] = (u32)__builtin_amdgcn_readlane((int)hv4.y, i);
      sh[4 * i + 2] = (u32)__builtin_amdgcn_readlane((int)hv4.z, i);
      sh[4 * i + 3] = (u32)__builtin_amdgcn_readlane((int)hv4.w, i);
    }
    float acc[4] = {0.f, 0.f, 0.f, 0.f};
    __builtin_amdgcn_s_setprio(1);
#pragma unroll
    for (int pp = 0; pp < 6; ++pp) {        // register-resident weights
#pragma unroll
      for (int cc = 0; cc < 4; ++cc) {
        acc[cc] = fdot2a(sh[pp * 4 + 0], wreg[cc * 24 + pp * 4 + 0], acc[cc]);
        acc[cc] = fdot2a(sh[pp * 4 + 1], wreg[cc * 24 + pp * 4 + 1], acc[cc]);
        acc[cc] = fdot2a(sh[pp * 4 + 2], wreg[cc * 24 + pp * 4 + 2], acc[cc]);
        acc[cc] = fdot2a(sh[pp * 4 + 3], wreg[cc * 24 + pp * 4 + 3], acc[cc]);
      }
    }
#pragma unroll
    for (int pp = 6; pp < 8; ++pp) {        // LDS-resident weights
#pragma unroll
      for (int cc = 0; cc < 4; ++cc) {
        uint4 wv = ldsW[(cc * 2 + (pp - 6)) * 1024 + t];
        acc[cc] = fdot2a(sh[pp * 4 + 0], wv.x, acc[cc]);
        acc[cc] = fdot2a(sh[pp * 4 + 1], wv.y, acc[cc]);
        acc[cc] = fdot2a(sh[pp * 4 + 2], wv.z, acc[cc]);
        acc[cc] = fdot2a(sh[pp * 4 + 3], wv.w, acc[cc]);
      }
    }
    __builtin_amdgcn_s_setprio(0);
    // ---- stage partial sums: one b128 per thread, row = quarter
    *(float4*)&zpart[qw * 1024 + jb] = *(float4*)acc;
    __syncthreads();
    // ---- act phase: t<256 sums 4 quarter-partials per gate, gate math
    if (t < 256) {
      const uint2 gx = pre;
      if (tc + 1 < Tc) pre = *(const uint2*)(gxp + (size_t)(tc + 1) * 1024);
      float z0 = zpart[0 * 1024 + 0 * 256 + t] + zpart[1 * 1024 + 0 * 256 + t]
               + zpart[2 * 1024 + 0 * 256 + t] + zpart[3 * 1024 + 0 * 256 + t];
      float z1 = zpart[0 * 1024 + 1 * 256 + t] + zpart[1 * 1024 + 1 * 256 + t]
               + zpart[2 * 1024 + 1 * 256 + t] + zpart[3 * 1024 + 1 * 256 + t];
      float z2 = zpart[0 * 1024 + 2 * 256 + t] + zpart[1 * 1024 + 2 * 256 + t]
               + zpart[2 * 1024 + 2 * 256 + t] + zpart[3 * 1024 + 2 * 256 + t];
      float z3 = zpart[0 * 1024 + 3 * 256 + t] + zpart[1 * 1024 + 3 * 256 + t]
               + zpart[2 * 1024 + 3 * 256 + t] + zpart[3 * 1024 + 3 * 256 + t];
      float zi = z0 + h2f((u16)(gx.x & 0xffff));
      float zf = z1 + h2f((u16)(gx.x >> 16));
      float zg = z2 + h2f((u16)(gx.y & 0xffff));
      float zo = z3 + h2f((u16)(gx.y >> 16));
      float i_ = sigmoidf_(zi), f_ = sigmoidf_(zf), g_ = tanhf_(zg), o_ = sigmoidf_(zo);
      c = f_ * c + i_ * g_;
      float h_ = o_ * tanhf_(c);
      const int kk = t >> 1;
      ((u16*)(hq + (buf ^ 1) * 160))[((kk >> 5) * 40 + (kk & 31)) * 2 + (t & 1)] = f16bits(h_);
    }
    buf ^= 1;
    __syncthreads();
  }

  if (t < 128) h16s[b * 128 + t] = hq[buf * 160 + (t >> 5) * 40 + (t & 31)];
  if (t < 256) c_s[b * 256 + t] = c;

  if (last && t < 128) {                    // y = h_T @ W_hy + b_y
    float acc = by[t];
    const u16* hh = (const u16*)(hq + buf * 160);
#pragma unroll 8
    for (int k = 0; k < 256; ++k) {
      float hv = h2f(hh[((k >> 6) * 40 + ((k >> 1) & 31)) * 2 + (k & 1)]);
      acc += hv * Why[k * 128 + t];
    }
    out[b * 128 + t] = acc;
  }
}

extern "C" void kernel_launch(void* const* d_in, const int* in_sizes, int n_in,
                              void* d_out, int out_size, void* d_ws, size_t ws_size,
                              hipStream_t stream) {
  const float* x   = (const float*)d_in[0];
  const float* Wxi = (const float*)d_in[1];
  const float* Whi = (const float*)d_in[2];
  const float* b_i = (const float*)d_in[3];
  const float* Wxf = (const float*)d_in[4];
  const float* Whf = (const float*)d_in[5];
  const float* b_f = (const float*)d_in[6];
  const float* Wxg = (const float*)d_in[7];
  const float* Whg = (const float*)d_in[8];
  const float* b_g = (const float*)d_in[9];
  const float* Wxo = (const float*)d_in[10];
  const float* Who = (const float*)d_in[11];
  const float* b_o = (const float*)d_in[12];
  const float* Why = (const float*)d_in[13];
  const float* b_y = (const float*)d_in[14];
  float* out = (float*)d_out;

  int Tc = 256;
  while (Tc > 32 && (size_t)128 * Tc * 1024 * 2 + 1245184ull > ws_size) Tc >>= 1;
  const int tcShift = __builtin_ctz((unsigned)Tc);
  const int nch = 1024 / Tc;

  char* wsb = (char*)d_ws;
  const size_t gbytes = (size_t)128 * Tc * 1024 * 2;
  u16*   gates16 = (u16*)wsb;
  u16*   WxT     = (u16*)(wsb + gbytes);
  u32*   Whpp    = (u32*)(wsb + gbytes + 524288);
  u32*   h16s    = (u32*)(wsb + gbytes + 1048576);
  float* c_s     = (float*)(wsb + gbytes + 1048576 + 65536);

  const int recLds = 131072 + 1280 + 16384;
  (void)hipFuncSetAttribute((const void*)lstm_rec,
                            hipFuncAttributeMaxDynamicSharedMemorySize, recLds);

  lstm_prep<<<1728, 256, 0, stream>>>(Wxi, Wxf, Wxg, Wxo, Whi, Whf, Whg, Who,
                                      WxT, Whpp, h16s, c_s);
  for (int ci = 0; ci < nch; ++ci) {
    int t0 = ci * Tc;
    proj_gemm<<<dim3(Tc, 8), 256, 0, stream>>>(x, WxT, gates16, b_i, b_f, b_g, b_o,
                                               t0, tcShift);
    lstm_rec<<<128, 1024, recLds, stream>>>(Whpp, gates16, h16s, c_s, Why, b_y, out,
                                            Tc, (ci == nch - 1) ? 1 : 0);
  }
}

// Round 11
// 1969.234 us; speedup vs baseline: 1.1142x; 1.1142x over previous
//
#include <hip/hip_runtime.h>

using u16 = unsigned short;
using u32 = unsigned int;

typedef _Float16 f16x2 __attribute__((ext_vector_type(2)));
typedef _Float16 f16x8 __attribute__((ext_vector_type(8)));
typedef float    f32x4 __attribute__((ext_vector_type(4)));

__device__ __forceinline__ u16 f16bits(float x) {
  union { _Float16 h; u16 u; } r; r.h = (_Float16)x; return r.u;
}
__device__ __forceinline__ float h2f(u16 v) {
  union { u16 u; _Float16 h; } r; r.u = v; return (float)r.h;
}
__device__ __forceinline__ u32 pack2(float a, float b) {
  union { f16x2 h; u32 u; } r; r.h.x = (_Float16)a; r.h.y = (_Float16)b; return r.u;
}
__device__ __forceinline__ float fdot2a(u32 a, u32 b, float c) {
  union { u32 u; f16x2 h; } ua, ub; ua.u = a; ub.u = b;
#if __has_builtin(__builtin_amdgcn_fdot2)
  return __builtin_amdgcn_fdot2(ua.h, ub.h, c, false);
#else
  return c + (float)ua.h.x * (float)ub.h.x + (float)ua.h.y * (float)ub.h.y;
#endif
}
__device__ __forceinline__ float sigmoidf_(float x) { return 1.0f / (1.0f + __expf(-x)); }
__device__ __forceinline__ float tanhf_(float x)    { return 1.0f - 2.0f / (__expf(2.0f * x) + 1.0f); }

__device__ __forceinline__ f16x8 lds16(const u16* p) {
  union { uint4 u; f16x8 h; } r; r.u = *(const uint4*)p; return r.h;
}

// Cross-quarter reduce on the VALU pipe (permlane swaps, NOT lds-bpermute).
__device__ __forceinline__ float qreduce(float a) {
#if __has_builtin(__builtin_amdgcn_permlane16_swap) && __has_builtin(__builtin_amdgcn_permlane32_swap)
  typedef unsigned uv2 __attribute__((ext_vector_type(2)));
  union { float f; unsigned u; } x, p, q;
  x.f = a;
  uv2 r1 = __builtin_amdgcn_permlane16_swap(x.u, x.u, false, false);
  p.u = r1[0]; q.u = r1[1];
  float s = p.f + q.f;
  x.f = s;
  uv2 r2 = __builtin_amdgcn_permlane32_swap(x.u, x.u, false, false);
  p.u = r2[0]; q.u = r2[1];
  return p.f + q.f;
#else
  a += __shfl_xor(a, 16);
  a += __shfl_xor(a, 32);
  return a;
#endif
}

// ---------------- prep: build f16 weight layouts + zero state ----------------
// WxT[n][k]   : [1024][256] f16, transposed input-proj weights
// Whpp[i4][t] : [64][512] uint4 — per-(rec-)thread gathered W_h pair groups.
//   rec thread t (of 512): w=t>>6 (8 waves), l=t&63, q=l>>4;
//   col(cc) = w*128 + (l&15)*8 + cc (cc 0..7); i4 = cc*8+pp (pp 0..7);
//   element e of uint4 = f16x2 pair kk = q*32+pp*4+e of column col.
// h16s        : [128][128] u32 pairs of h state, zeroed
// c_s         : [128][256] f32, zeroed
__global__ void lstm_prep(const float* __restrict__ Wxi, const float* __restrict__ Wxf,
                          const float* __restrict__ Wxg, const float* __restrict__ Wxo,
                          const float* __restrict__ Whi, const float* __restrict__ Whf,
                          const float* __restrict__ Whg, const float* __restrict__ Who,
                          u16* __restrict__ WxT, u32* __restrict__ Whpp,
                          u32* __restrict__ h16s, float* __restrict__ c_s) {
  int idx = blockIdx.x * 256 + threadIdx.x;
  if (idx < 262144) {                       // WxT
    int n = idx >> 8, k = idx & 255;
    int g = n >> 8;
    const float* W = (g == 0) ? Wxi : (g == 1) ? Wxf : (g == 2) ? Wxg : Wxo;
    WxT[idx] = f16bits(W[k * 256 + (n & 255)]);
  } else if (idx < 262144 + 131072) {       // Whpp (u32-granular writes)
    int i2 = idx - 262144;
    int e = i2 & 3, tmp = i2 >> 2;
    int t = tmp & 511, i4 = tmp >> 9;       // t in [0,512), i4 in [0,64)
    int cc = i4 >> 3, pp = i4 & 7;
    int w = t >> 6, l = t & 63, q = l >> 4;
    int j = w * 128 + (l & 15) * 8 + cc;    // owned column
    int kk = q * 32 + pp * 4 + e;
    int g = j >> 8, col = j & 255;
    const float* W = (g == 0) ? Whi : (g == 1) ? Whf : (g == 2) ? Whg : Who;
    u32 lo = f16bits(W[(2 * kk) * 256 + col]);
    u32 hi = f16bits(W[(2 * kk + 1) * 256 + col]);
    Whpp[i2] = lo | (hi << 16);
  } else if (idx < 262144 + 131072 + 16384) {
    h16s[idx - 393216] = 0u;
  } else if (idx < 262144 + 131072 + 16384 + 32768) {
    c_s[idx - 409600] = 0.0f;
  }
}

// ---------------- input-projection GEMM (R2/R9-proven, plain gates layout) ---
__global__ __launch_bounds__(256) void proj_gemm(
    const float* __restrict__ x, const u16* __restrict__ WxT,
    u16* __restrict__ gates, const float* __restrict__ bi,
    const float* __restrict__ bf, const float* __restrict__ bg,
    const float* __restrict__ bo, int t0, int tcShift) {
  __shared__ u16 Al[128 * 72];
  __shared__ u16 Bl[128 * 72];
  const int tid = threadIdx.x;
  const int lane = tid & 63, wv = tid >> 6;
  const int wr = wv >> 1, wc = wv & 1;
  const int m0 = blockIdx.x * 128, n0 = blockIdx.y * 128;
  const int tcMask = (1 << tcShift) - 1;
  f32x4 acc[4][4] = {};
  for (int k0 = 0; k0 < 256; k0 += 64) {
#pragma unroll
    for (int p = 0; p < 8; ++p) {
      int flat = p * 256 + tid;
      int r = flat >> 4, cc = flat & 15;
      int m = m0 + r;
      int b = m >> tcShift, tc = m & tcMask;
      const float4 xv = *(const float4*)(x + (size_t)(b * 1024 + t0 + tc) * 256 + k0 + cc * 4);
      uint2 w2 = make_uint2(pack2(xv.x, xv.y), pack2(xv.z, xv.w));
      *(uint2*)&Al[r * 72 + cc * 4] = w2;
    }
#pragma unroll
    for (int p = 0; p < 8; ++p) {
      int flat = p * 256 + tid;
      int r = flat >> 4, cc = flat & 15;
      uint2 w2 = *(const uint2*)(WxT + (size_t)(n0 + r) * 256 + k0 + cc * 4);
      *(uint2*)&Bl[r * 72 + cc * 4] = w2;
    }
    __syncthreads();
#pragma unroll
    for (int kk = 0; kk < 64; kk += 32) {
      f16x8 af[4], bfr[4];
#pragma unroll
      for (int i = 0; i < 4; ++i) {
        af[i]  = lds16(&Al[(wr * 64 + i * 16 + (lane & 15)) * 72 + kk + (lane >> 4) * 8]);
        bfr[i] = lds16(&Bl[(wc * 64 + i * 16 + (lane & 15)) * 72 + kk + (lane >> 4) * 8]);
      }
#pragma unroll
      for (int mi = 0; mi < 4; ++mi)
#pragma unroll
        for (int ni = 0; ni < 4; ++ni)
          acc[mi][ni] = __builtin_amdgcn_mfma_f32_16x16x32_f16(af[mi], bfr[ni], acc[mi][ni], 0, 0, 0);
    }
    __syncthreads();
  }
#pragma unroll
  for (int ni = 0; ni < 4; ++ni) {
    int n = n0 + wc * 64 + ni * 16 + (lane & 15);
    int g = n >> 8;
    const float* bp = (g == 0) ? bi : (g == 1) ? bf : (g == 2) ? bg : bo;
    float bias = bp[n & 255];
#pragma unroll
    for (int mi = 0; mi < 4; ++mi) {
#pragma unroll
      for (int ri = 0; ri < 4; ++ri) {
        int m = m0 + wr * 64 + mi * 16 + (lane >> 4) * 4 + ri;
        gates[(size_t)m * 1024 + n] = f16bits(acc[mi][ni][ri] + bias);
      }
    }
  }
}

// ---------------- persistent per-batch recurrence (R9 structure @ 8 waves) ---
// 512 threads, 8 waves, 2 waves/SIMD -> 256-reg budget. thread t (w=t>>6,
// l=t&63, q=l>>4): owns 8 consecutive cols jb..jb+7 (jb=w*128+(l&15)*8),
// K-quarter q. Weights: pp 0..5 in regs (192 u32), pp 6..7 in LDS
// ([16][512] uint4, 16 x ds_read_b128/thread/step).
// h-broadcast redundancy halves vs 16 waves (64 vs 128 wave-b128/step).
// Wave-parity STAGGER + setprio; permlane qreduce; zbuf + act phase (t<256);
// 2 barriers/step.
__global__ __launch_bounds__(512, 2) void lstm_rec(
    const u32* __restrict__ Whpp, const u16* __restrict__ gates,
    u32* __restrict__ h16s, float* __restrict__ c_s,
    const float* __restrict__ Why, const float* __restrict__ by,
    float* __restrict__ out, int Tc, int last) {
  extern __shared__ unsigned char smem[];
  uint4* ldsW = (uint4*)smem;                       // [16][512] uint4 = 131072 B
  u32*   hq   = (u32*)(smem + 131072);              // [2][4*40] u32   = 1280 B
  float* zbuf = (float*)(smem + 131072 + 1280);     // [1024] f32      = 4096 B
  const int b = blockIdx.x, t = threadIdx.x;
  const int l = t & 63, w = t >> 6, q = l >> 4;
  const int jb = w * 128 + (l & 15) * 8;            // first of 8 owned cols

  // gather weights: 64 coalesced uint4 loads; pp<6 -> regs, pp>=6 -> LDS
  u32 wreg[192];
  const uint4* Wp4 = (const uint4*)Whpp;
#pragma unroll
  for (int i4 = 0; i4 < 64; ++i4) {
    uint4 v = Wp4[i4 * 512 + t];
    const int cc = i4 >> 3, pp = i4 & 7;
    if (pp < 6) {
      wreg[cc * 24 + pp * 4 + 0] = v.x;
      wreg[cc * 24 + pp * 4 + 1] = v.y;
      wreg[cc * 24 + pp * 4 + 2] = v.z;
      wreg[cc * 24 + pp * 4 + 3] = v.w;
    } else {
      ldsW[(cc * 2 + (pp - 6)) * 512 + t] = v;
    }
  }
  if (t < 128) hq[(t >> 5) * 40 + (t & 31)] = h16s[b * 128 + t];
  float c = 0.0f;
  if (t < 256) c = c_s[b * 256 + t];
  const u16* gxp = gates + (size_t)b * Tc * 1024 + jb;
  uint4 pre = *(const uint4*)gxp;                   // 8 gate pre-acts (8 cols)
  int buf = 0;
  const int evenWave = ((w & 1) == 0);
  __syncthreads();

#define REGDOTS                                                         \
  _Pragma("unroll")                                                     \
  for (int pp = 0; pp < 6; ++pp) {                                      \
    uint4 hv = hb[pp];                                                  \
    _Pragma("unroll")                                                   \
    for (int cc = 0; cc < 8; ++cc) {                                    \
      acc[cc] = fdot2a(hv.x, wreg[cc * 24 + pp * 4 + 0], acc[cc]);      \
      acc[cc] = fdot2a(hv.y, wreg[cc * 24 + pp * 4 + 1], acc[cc]);      \
      acc[cc] = fdot2a(hv.z, wreg[cc * 24 + pp * 4 + 2], acc[cc]);      \
      acc[cc] = fdot2a(hv.w, wreg[cc * 24 + pp * 4 + 3], acc[cc]);      \
    }                                                                   \
  }
#define LDSDOTS                                                         \
  _Pragma("unroll")                                                     \
  for (int pp = 6; pp < 8; ++pp) {                                      \
    uint4 hv = hb[pp];                                                  \
    _Pragma("unroll")                                                   \
    for (int cc = 0; cc < 8; ++cc) {                                    \
      uint4 wv = ldsW[(cc * 2 + (pp - 6)) * 512 + t];                   \
      acc[cc] = fdot2a(hv.x, wv.x, acc[cc]);                            \
      acc[cc] = fdot2a(hv.y, wv.y, acc[cc]);                            \
      acc[cc] = fdot2a(hv.z, wv.z, acc[cc]);                            \
      acc[cc] = fdot2a(hv.w, wv.w, acc[cc]);                            \
    }                                                                   \
  }

  for (int tc = 0; tc < Tc; ++tc) {
    const uint4 gx = pre;
    if (tc + 1 < Tc) pre = *(const uint4*)(gxp + (size_t)(tc + 1) * 1024);
    float acc[8] = {0.f, 0.f, 0.f, 0.f, 0.f, 0.f, 0.f, 0.f};
    const uint4* hb = (const uint4*)(hq + buf * 160 + q * 40);
    __builtin_amdgcn_s_setprio(1);
    if (evenWave) {
      REGDOTS
      LDSDOTS
    } else {
      LDSDOTS
      REGDOTS
    }
    __builtin_amdgcn_s_setprio(0);
#pragma unroll
    for (int i = 0; i < 8; ++i) acc[i] = qreduce(acc[i]);
    if (l < 16) {
      float4 z4a, z4b;
      z4a.x = acc[0] + h2f((u16)(gx.x & 0xffff));
      z4a.y = acc[1] + h2f((u16)(gx.x >> 16));
      z4a.z = acc[2] + h2f((u16)(gx.y & 0xffff));
      z4a.w = acc[3] + h2f((u16)(gx.y >> 16));
      z4b.x = acc[4] + h2f((u16)(gx.z & 0xffff));
      z4b.y = acc[5] + h2f((u16)(gx.z >> 16));
      z4b.z = acc[6] + h2f((u16)(gx.w & 0xffff));
      z4b.w = acc[7] + h2f((u16)(gx.w >> 16));
      *(float4*)&zbuf[jb] = z4a;
      *(float4*)&zbuf[jb + 4] = z4b;
    }
    __syncthreads();
    if (t < 256) {
      float zi = zbuf[t], zf = zbuf[t + 256], zg = zbuf[t + 512], zo = zbuf[t + 768];
      float i_ = sigmoidf_(zi), f_ = sigmoidf_(zf), g_ = tanhf_(zg), o_ = sigmoidf_(zo);
      c = f_ * c + i_ * g_;
      float h_ = o_ * tanhf_(c);
      const int kk = t >> 1;
      ((u16*)(hq + (buf ^ 1) * 160))[((kk >> 5) * 40 + (kk & 31)) * 2 + (t & 1)] = f16bits(h_);
    }
    buf ^= 1;
    __syncthreads();
  }
#undef REGDOTS
#undef LDSDOTS

  if (t < 128) h16s[b * 128 + t] = hq[buf * 160 + (t >> 5) * 40 + (t & 31)];
  if (t < 256) c_s[b * 256 + t] = c;

  if (last && t < 128) {                    // y = h_T @ W_hy + b_y
    float acc = by[t];
    const u16* hh = (const u16*)(hq + buf * 160);
#pragma unroll 8
    for (int k = 0; k < 256; ++k) {
      float hv = h2f(hh[((k >> 6) * 40 + ((k >> 1) & 31)) * 2 + (k & 1)]);
      acc += hv * Why[k * 128 + t];
    }
    out[b * 128 + t] = acc;
  }
}

extern "C" void kernel_launch(void* const* d_in, const int* in_sizes, int n_in,
                              void* d_out, int out_size, void* d_ws, size_t ws_size,
                              hipStream_t stream) {
  const float* x   = (const float*)d_in[0];
  const float* Wxi = (const float*)d_in[1];
  const float* Whi = (const float*)d_in[2];
  const float* b_i = (const float*)d_in[3];
  const float* Wxf = (const float*)d_in[4];
  const float* Whf = (const float*)d_in[5];
  const float* b_f = (const float*)d_in[6];
  const float* Wxg = (const float*)d_in[7];
  const float* Whg = (const float*)d_in[8];
  const float* b_g = (const float*)d_in[9];
  const float* Wxo = (const float*)d_in[10];
  const float* Who = (const float*)d_in[11];
  const float* b_o = (const float*)d_in[12];
  const float* Why = (const float*)d_in[13];
  const float* b_y = (const float*)d_in[14];
  float* out = (float*)d_out;

  int Tc = 256;
  while (Tc > 32 && (size_t)128 * Tc * 1024 * 2 + 1245184ull > ws_size) Tc >>= 1;
  const int tcShift = __builtin_ctz((unsigned)Tc);
  const int nch = 1024 / Tc;

  char* wsb = (char*)d_ws;
  const size_t gbytes = (size_t)128 * Tc * 1024 * 2;
  u16*   gates16 = (u16*)wsb;
  u16*   WxT     = (u16*)(wsb + gbytes);
  u32*   Whpp    = (u32*)(wsb + gbytes + 524288);
  u32*   h16s    = (u32*)(wsb + gbytes + 1048576);
  float* c_s     = (float*)(wsb + gbytes + 1048576 + 65536);

  const int recLds = 131072 + 1280 + 4096;
  (void)hipFuncSetAttribute((const void*)lstm_rec,
                            hipFuncAttributeMaxDynamicSharedMemorySize, recLds);

  lstm_prep<<<1728, 256, 0, stream>>>(Wxi, Wxf, Wxg, Wxo, Whi, Whf, Whg, Who,
                                      WxT, Whpp, h16s, c_s);
  for (int ci = 0; ci < nch; ++ci) {
    int t0 = ci * Tc;
    proj_gemm<<<dim3(Tc, 8), 256, 0, stream>>>(x, WxT, gates16, b_i, b_f, b_g, b_o,
                                               t0, tcShift);
    lstm_rec<<<128, 512, recLds, stream>>>(Whpp, gates16, h16s, c_s, Why, b_y, out,
                                           Tc, (ci == nch - 1) ? 1 : 0);
  }
}

// Round 12
// 1852.757 us; speedup vs baseline: 1.1842x; 1.0629x over previous
//
#include <hip/hip_runtime.h>

using u16 = unsigned short;
using u32 = unsigned int;

typedef _Float16 f16x2 __attribute__((ext_vector_type(2)));
typedef _Float16 f16x8 __attribute__((ext_vector_type(8)));
typedef float    f32x4 __attribute__((ext_vector_type(4)));

__device__ __forceinline__ u16 f16bits(float x) {
  union { _Float16 h; u16 u; } r; r.h = (_Float16)x; return r.u;
}
__device__ __forceinline__ float h2f(u16 v) {
  union { u16 u; _Float16 h; } r; r.u = v; return (float)r.h;
}
__device__ __forceinline__ u32 pack2(float a, float b) {
  union { f16x2 h; u32 u; } r; r.h.x = (_Float16)a; r.h.y = (_Float16)b; return r.u;
}
__device__ __forceinline__ float fdot2a(u32 a, u32 b, float c) {
  union { u32 u; f16x2 h; } ua, ub; ua.u = a; ub.u = b;
#if __has_builtin(__builtin_amdgcn_fdot2)
  return __builtin_amdgcn_fdot2(ua.h, ub.h, c, false);
#else
  return c + (float)ua.h.x * (float)ub.h.x + (float)ua.h.y * (float)ub.h.y;
#endif
}
__device__ __forceinline__ float sigmoidf_(float x) { return 1.0f / (1.0f + __expf(-x)); }
__device__ __forceinline__ float tanhf_(float x)    { return 1.0f - 2.0f / (__expf(2.0f * x) + 1.0f); }

__device__ __forceinline__ f16x8 lds16(const u16* p) {
  union { uint4 u; f16x8 h; } r; r.u = *(const uint4*)p; return r.h;
}

// Cross-quarter reduce on the VALU pipe (permlane swaps, NOT lds-bpermute).
__device__ __forceinline__ float qreduce(float a) {
#if __has_builtin(__builtin_amdgcn_permlane16_swap) && __has_builtin(__builtin_amdgcn_permlane32_swap)
  typedef unsigned uv2 __attribute__((ext_vector_type(2)));
  union { float f; unsigned u; } x, p, q;
  x.f = a;
  uv2 r1 = __builtin_amdgcn_permlane16_swap(x.u, x.u, false, false);
  p.u = r1[0]; q.u = r1[1];
  float s = p.f + q.f;
  x.f = s;
  uv2 r2 = __builtin_amdgcn_permlane32_swap(x.u, x.u, false, false);
  p.u = r2[0]; q.u = r2[1];
  return p.f + q.f;
#else
  a += __shfl_xor(a, 16);
  a += __shfl_xor(a, 32);
  return a;
#endif
}

// ---------------- prep: build f16 weight layouts + zero state ----------------
// WxT[n][k]   : [1024][256] f16, transposed input-proj weights
// Whpp[i4][t] : [32][1024] uint4 — per-(rec-)thread gathered W_h pair groups.
//   thread t: w=t>>6, l=t&63, q=l>>4; col(cc)=w*64+(l&15)*4+cc; i4=cc*8+pp;
//   element e of uint4 = f16x2 pair kk = q*32+pp*4+e of column cc.
// h16s        : [128][128] u32 pairs of h state, zeroed
// c_s         : [128][256] f32, zeroed
__global__ void lstm_prep(const float* __restrict__ Wxi, const float* __restrict__ Wxf,
                          const float* __restrict__ Wxg, const float* __restrict__ Wxo,
                          const float* __restrict__ Whi, const float* __restrict__ Whf,
                          const float* __restrict__ Whg, const float* __restrict__ Who,
                          u16* __restrict__ WxT, u32* __restrict__ Whpp,
                          u32* __restrict__ h16s, float* __restrict__ c_s) {
  int idx = blockIdx.x * 256 + threadIdx.x;
  if (idx < 262144) {                       // WxT
    int n = idx >> 8, k = idx & 255;
    int g = n >> 8;
    const float* W = (g == 0) ? Wxi : (g == 1) ? Wxf : (g == 2) ? Wxg : Wxo;
    WxT[idx] = f16bits(W[k * 256 + (n & 255)]);
  } else if (idx < 262144 + 131072) {       // Whpp (u32-granular writes)
    int i2 = idx - 262144;
    int e = i2 & 3, tmp = i2 >> 2;
    int t = tmp & 1023, i4 = tmp >> 10;
    int cc = i4 >> 3, pp = i4 & 7;
    int w = t >> 6, l = t & 63, q = l >> 4;
    int j = w * 64 + (l & 15) * 4 + cc;
    int kk = q * 32 + pp * 4 + e;
    int g = j >> 8, col = j & 255;
    const float* W = (g == 0) ? Whi : (g == 1) ? Whf : (g == 2) ? Whg : Who;
    u32 lo = f16bits(W[(2 * kk) * 256 + col]);
    u32 hi = f16bits(W[(2 * kk + 1) * 256 + col]);
    Whpp[i2] = lo | (hi << 16);
  } else if (idx < 262144 + 131072 + 16384) {
    h16s[idx - 393216] = 0u;
  } else if (idx < 262144 + 131072 + 16384 + 32768) {
    c_s[idx - 409600] = 0.0f;
  }
}

// ---------------- input-projection GEMM (R2-proven, non-permuted gates) ------
__global__ __launch_bounds__(256) void proj_gemm(
    const float* __restrict__ x, const u16* __restrict__ WxT,
    u16* __restrict__ gates, const float* __restrict__ bi,
    const float* __restrict__ bf, const float* __restrict__ bg,
    const float* __restrict__ bo, int t0, int tcShift) {
  __shared__ u16 Al[128 * 72];
  __shared__ u16 Bl[128 * 72];
  const int tid = threadIdx.x;
  const int lane = tid & 63, wv = tid >> 6;
  const int wr = wv >> 1, wc = wv & 1;
  const int m0 = blockIdx.x * 128, n0 = blockIdx.y * 128;
  const int tcMask = (1 << tcShift) - 1;
  f32x4 acc[4][4] = {};
  for (int k0 = 0; k0 < 256; k0 += 64) {
#pragma unroll
    for (int p = 0; p < 8; ++p) {
      int flat = p * 256 + tid;
      int r = flat >> 4, cc = flat & 15;
      int m = m0 + r;
      int b = m >> tcShift, tc = m & tcMask;
      const float4 xv = *(const float4*)(x + (size_t)(b * 1024 + t0 + tc) * 256 + k0 + cc * 4);
      uint2 w2 = make_uint2(pack2(xv.x, xv.y), pack2(xv.z, xv.w));
      *(uint2*)&Al[r * 72 + cc * 4] = w2;
    }
#pragma unroll
    for (int p = 0; p < 8; ++p) {
      int flat = p * 256 + tid;
      int r = flat >> 4, cc = flat & 15;
      uint2 w2 = *(const uint2*)(WxT + (size_t)(n0 + r) * 256 + k0 + cc * 4);
      *(uint2*)&Bl[r * 72 + cc * 4] = w2;
    }
    __syncthreads();
#pragma unroll
    for (int kk = 0; kk < 64; kk += 32) {
      f16x8 af[4], bfr[4];
#pragma unroll
      for (int i = 0; i < 4; ++i) {
        af[i]  = lds16(&Al[(wr * 64 + i * 16 + (lane & 15)) * 72 + kk + (lane >> 4) * 8]);
        bfr[i] = lds16(&Bl[(wc * 64 + i * 16 + (lane & 15)) * 72 + kk + (lane >> 4) * 8]);
      }
#pragma unroll
      for (int mi = 0; mi < 4; ++mi)
#pragma unroll
        for (int ni = 0; ni < 4; ++ni)
          acc[mi][ni] = __builtin_amdgcn_mfma_f32_16x16x32_f16(af[mi], bfr[ni], acc[mi][ni], 0, 0, 0);
    }
    __syncthreads();
  }
#pragma unroll
  for (int ni = 0; ni < 4; ++ni) {
    int n = n0 + wc * 64 + ni * 16 + (lane & 15);
    int g = n >> 8;
    const float* bp = (g == 0) ? bi : (g == 1) ? bf : (g == 2) ? bg : bo;
    float bias = bp[n & 255];
#pragma unroll
    for (int mi = 0; mi < 4; ++mi) {
#pragma unroll
      for (int ri = 0; ri < 4; ++ri) {
        int m = m0 + wr * 64 + mi * 16 + (lane >> 4) * 4 + ri;
        gates[(size_t)m * 1024 + n] = f16bits(acc[mi][ni][ri] + bias);
      }
    }
  }
}

// ---------------- persistent per-batch recurrence (R9: measured best) --------
// 1024 threads. thread t (w=t>>6, l=t&63, q=l>>4): owns 4 consecutive cols
// jb..jb+3 (jb=w*64+(l&15)*4), K-quarter q. Weights: pp 0..5 in regs (96 u32),
// pp 6..7 in LDS [8][1024] uint4 (8 x ds_read_b128/thread/step).
// Wave-parity STAGGER: even waves run reg-dots then LDS-dots; odd waves the
// reverse -> half the waves use VALU while half use the LDS pipe.
// permlane qreduce (VALU); zbuf + act phase on t<256 (R2-proven); 2 barriers.
__global__ __launch_bounds__(1024) void lstm_rec(
    const u32* __restrict__ Whpp, const u16* __restrict__ gates,
    u32* __restrict__ h16s, float* __restrict__ c_s,
    const float* __restrict__ Why, const float* __restrict__ by,
    float* __restrict__ out, int Tc, int last) {
  extern __shared__ unsigned char smem[];
  uint4* ldsW = (uint4*)smem;                       // [8][1024] uint4 = 131072 B
  u32*   hq   = (u32*)(smem + 131072);              // [2][4*40] u32   = 1280 B
  float* zbuf = (float*)(smem + 131072 + 1280);     // [1024] f32      = 4096 B
  const int b = blockIdx.x, t = threadIdx.x;
  const int l = t & 63, w = t >> 6, q = l >> 4;
  const int jb = w * 64 + (l & 15) * 4;             // first of 4 owned cols

  // gather weights: 32 coalesced uint4 loads; pp<6 -> regs, pp>=6 -> LDS
  u32 wreg[96];
  const uint4* Wp4 = (const uint4*)Whpp;
#pragma unroll
  for (int i4 = 0; i4 < 32; ++i4) {
    uint4 v = Wp4[i4 * 1024 + t];
    const int cc = i4 >> 3, pp = i4 & 7;
    if (pp < 6) {
      wreg[cc * 24 + pp * 4 + 0] = v.x;
      wreg[cc * 24 + pp * 4 + 1] = v.y;
      wreg[cc * 24 + pp * 4 + 2] = v.z;
      wreg[cc * 24 + pp * 4 + 3] = v.w;
    } else {
      ldsW[(cc * 2 + (pp - 6)) * 1024 + t] = v;
    }
  }
  if (t < 128) hq[(t >> 5) * 40 + (t & 31)] = h16s[b * 128 + t];
  float c = 0.0f;
  if (t < 256) c = c_s[b * 256 + t];
  const u16* gxp = gates + (size_t)b * Tc * 1024 + jb;
  uint2 pre = *(const uint2*)gxp;
  int buf = 0;
  const int evenWave = ((w & 1) == 0);
  __syncthreads();

#define REGDOTS                                                         \
  _Pragma("unroll")                                                     \
  for (int pp = 0; pp < 6; ++pp) {                                      \
    uint4 hv = hb[pp];                                                  \
    _Pragma("unroll")                                                   \
    for (int cc = 0; cc < 4; ++cc) {                                    \
      acc[cc] = fdot2a(hv.x, wreg[cc * 24 + pp * 4 + 0], acc[cc]);      \
      acc[cc] = fdot2a(hv.y, wreg[cc * 24 + pp * 4 + 1], acc[cc]);      \
      acc[cc] = fdot2a(hv.z, wreg[cc * 24 + pp * 4 + 2], acc[cc]);      \
      acc[cc] = fdot2a(hv.w, wreg[cc * 24 + pp * 4 + 3], acc[cc]);      \
    }                                                                   \
  }
#define LDSDOTS                                                         \
  _Pragma("unroll")                                                     \
  for (int pp = 6; pp < 8; ++pp) {                                      \
    uint4 hv = hb[pp];                                                  \
    _Pragma("unroll")                                                   \
    for (int cc = 0; cc < 4; ++cc) {                                    \
      uint4 wv = ldsW[(cc * 2 + (pp - 6)) * 1024 + t];                  \
      acc[cc] = fdot2a(hv.x, wv.x, acc[cc]);                            \
      acc[cc] = fdot2a(hv.y, wv.y, acc[cc]);                            \
      acc[cc] = fdot2a(hv.z, wv.z, acc[cc]);                            \
      acc[cc] = fdot2a(hv.w, wv.w, acc[cc]);                            \
    }                                                                   \
  }

  for (int tc = 0; tc < Tc; ++tc) {
    const uint2 gx = pre;
    if (tc + 1 < Tc) pre = *(const uint2*)(gxp + (size_t)(tc + 1) * 1024);
    float acc[4] = {0.f, 0.f, 0.f, 0.f};
    const uint4* hb = (const uint4*)(hq + buf * 160 + q * 40);
    __builtin_amdgcn_s_setprio(1);
    if (evenWave) {
      REGDOTS
      LDSDOTS
    } else {
      LDSDOTS
      REGDOTS
    }
    __builtin_amdgcn_s_setprio(0);
    acc[0] = qreduce(acc[0]);
    acc[1] = qreduce(acc[1]);
    acc[2] = qreduce(acc[2]);
    acc[3] = qreduce(acc[3]);
    if (l < 16) {
      float4 z4;
      z4.x = acc[0] + h2f((u16)(gx.x & 0xffff));
      z4.y = acc[1] + h2f((u16)(gx.x >> 16));
      z4.z = acc[2] + h2f((u16)(gx.y & 0xffff));
      z4.w = acc[3] + h2f((u16)(gx.y >> 16));
      *(float4*)&zbuf[jb] = z4;
    }
    __syncthreads();
    if (t < 256) {
      float zi = zbuf[t], zf = zbuf[t + 256], zg = zbuf[t + 512], zo = zbuf[t + 768];
      float i_ = sigmoidf_(zi), f_ = sigmoidf_(zf), g_ = tanhf_(zg), o_ = sigmoidf_(zo);
      c = f_ * c + i_ * g_;
      float h_ = o_ * tanhf_(c);
      const int kk = t >> 1;
      ((u16*)(hq + (buf ^ 1) * 160))[((kk >> 5) * 40 + (kk & 31)) * 2 + (t & 1)] = f16bits(h_);
    }
    buf ^= 1;
    __syncthreads();
  }
#undef REGDOTS
#undef LDSDOTS

  if (t < 128) h16s[b * 128 + t] = hq[buf * 160 + (t >> 5) * 40 + (t & 31)];
  if (t < 256) c_s[b * 256 + t] = c;

  if (last && t < 128) {                    // y = h_T @ W_hy + b_y
    float acc = by[t];
    const u16* hh = (const u16*)(hq + buf * 160);
#pragma unroll 8
    for (int k = 0; k < 256; ++k) {
      float hv = h2f(hh[((k >> 6) * 40 + ((k >> 1) & 31)) * 2 + (k & 1)]);
      acc += hv * Why[k * 128 + t];
    }
    out[b * 128 + t] = acc;
  }
}

extern "C" void kernel_launch(void* const* d_in, const int* in_sizes, int n_in,
                              void* d_out, int out_size, void* d_ws, size_t ws_size,
                              hipStream_t stream) {
  const float* x   = (const float*)d_in[0];
  const float* Wxi = (const float*)d_in[1];
  const float* Whi = (const float*)d_in[2];
  const float* b_i = (const float*)d_in[3];
  const float* Wxf = (const float*)d_in[4];
  const float* Whf = (const float*)d_in[5];
  const float* b_f = (const float*)d_in[6];
  const float* Wxg = (const float*)d_in[7];
  const float* Whg = (const float*)d_in[8];
  const float* b_g = (const float*)d_in[9];
  const float* Wxo = (const float*)d_in[10];
  const float* Who = (const float*)d_in[11];
  const float* b_o = (const float*)d_in[12];
  const float* Why = (const float*)d_in[13];
  const float* b_y = (const float*)d_in[14];
  float* out = (float*)d_out;

  int Tc = 256;
  while (Tc > 32 && (size_t)128 * Tc * 1024 * 2 + 1245184ull > ws_size) Tc >>= 1;
  const int tcShift = __builtin_ctz((unsigned)Tc);
  const int nch = 1024 / Tc;

  char* wsb = (char*)d_ws;
  const size_t gbytes = (size_t)128 * Tc * 1024 * 2;
  u16*   gates16 = (u16*)wsb;
  u16*   WxT     = (u16*)(wsb + gbytes);
  u32*   Whpp    = (u32*)(wsb + gbytes + 524288);
  u32*   h16s    = (u32*)(wsb + gbytes + 1048576);
  float* c_s     = (float*)(wsb + gbytes + 1048576 + 65536);

  const int recLds = 131072 + 1280 + 4096;
  (void)hipFuncSetAttribute((const void*)lstm_rec,
                            hipFuncAttributeMaxDynamicSharedMemorySize, recLds);

  lstm_prep<<<1728, 256, 0, stream>>>(Wxi, Wxf, Wxg, Wxo, Whi, Whf, Whg, Who,
                                      WxT, Whpp, h16s, c_s);
  for (int ci = 0; ci < nch; ++ci) {
    int t0 = ci * Tc;
    proj_gemm<<<dim3(Tc, 8), 256, 0, stream>>>(x, WxT, gates16, b_i, b_f, b_g, b_o,
                                               t0, tcShift);
    lstm_rec<<<128, 1024, recLds, stream>>>(Whpp, gates16, h16s, c_s, Why, b_y, out,
                                            Tc, (ci == nch - 1) ? 1 : 0);
  }
}